// Round 13
// baseline (350.230 us; speedup 1.0000x reference)
//
#include <hip/hip_runtime.h>
#include <hip/hip_bf16.h>
#include <math.h>

#define T_TOK 2048
#define HDIM 1024
#define IDIM 4096
#define NEXP 8
#define RROWS 3200    // 3072 usable routed rows + 128 guaranteed-zero dummy rows
#define AROWS 5248    // 2048 shared + RROWS
#define ZROW  5120    // absolute row of the 128 dummy zero rows (= T_TOK + 3072)
#define NP2   24      // pair-tile entries: 8 shared + <=15 routed + pad
#define BK 32

typedef unsigned int uint;
typedef unsigned short ushort;
typedef __attribute__((ext_vector_type(4))) float f32x4;
typedef __attribute__((ext_vector_type(8))) short bf16x8;

__device__ __forceinline__ ushort f2bf(float f) {
  union { float f; uint u; } c; c.f = f;
  uint u = c.u;
  return (ushort)((u + 0x7FFFu + ((u >> 16) & 1u)) >> 16);  // RNE
}
__device__ __forceinline__ uint cvtpk(float a, float b) {
  uint r;
  asm("v_cvt_pk_bf16_f32 %0, %1, %2" : "=v"(r) : "v"(a), "v"(b));
  return r;
}
__device__ __forceinline__ uint4 cvt8(const float4 a, const float4 b) {
  uint4 r;
  r.x = cvtpk(a.x, a.y); r.y = cvtpk(a.z, a.w);
  r.z = cvtpk(b.x, b.y); r.w = cvtpk(b.z, b.w);
  return r;
}
// async global->LDS, 16B per lane; LDS dest is wave-uniform base + lane*16
__device__ __forceinline__ void gld16(ushort* lds, const ushort* g) {
  __builtin_amdgcn_global_load_lds(
      (const __attribute__((address_space(1))) uint*)g,
      (__attribute__((address_space(3))) uint*)lds, 16, 0, 0);
}
__device__ __forceinline__ void gld16f(float* lds, const float* g) {
  __builtin_amdgcn_global_load_lds(
      (const __attribute__((address_space(1))) uint*)g,
      (__attribute__((address_space(3))) uint*)lds, 16, 0, 0);
}
// LDS tile layout (bf16 A): 16B slot (row,kc) -> ushort off (row>>4)*512 + kc*128 + (row&15)*8
__device__ __forceinline__ int soff(int row, int kc) {
  return ((row >> 4) << 9) + (kc << 7) + ((row & 15) << 3);
}

// counted-vmcnt barrier: keep newest N vmem ops in flight across the barrier
#define SYNCV(N) { \
  __builtin_amdgcn_sched_barrier(0); \
  asm volatile("s_waitcnt vmcnt(" #N ") lgkmcnt(0)" ::: "memory"); \
  __builtin_amdgcn_s_barrier(); \
  __builtin_amdgcn_sched_barrier(0); }

// ---------------- router: logits, top-1, sigmoid, scores out, hs->bf16 ----
__global__ __launch_bounds__(256) void router_kernel(
    const float* __restrict__ hs, const float* __restrict__ rw,
    ushort* __restrict__ Xall, float* __restrict__ scores_out,
    int* __restrict__ eidx, float* __restrict__ sval)
{
  const int wave = threadIdx.x >> 6;
  const int lane = threadIdx.x & 63;
  const int t = blockIdx.x * 4 + wave;
  const float* row = hs + (size_t)t * HDIM;
  float v[16];
  #pragma unroll
  for (int i = 0; i < 16; ++i) {
    v[i] = row[lane + 64 * i];
    Xall[(size_t)t * HDIM + lane + 64 * i] = f2bf(v[i]);
  }
  float logit[8];
  #pragma unroll
  for (int e = 0; e < 8; ++e) {
    const float* wr = rw + e * HDIM;
    float s = 0.f;
    #pragma unroll
    for (int i = 0; i < 16; ++i) s += v[i] * wr[lane + 64 * i];
    #pragma unroll
    for (int off = 32; off; off >>= 1) s += __shfl_xor(s, off, 64);
    logit[e] = s;
  }
  if (lane == 0) {
    int be = 0; float bv = logit[0];
    #pragma unroll
    for (int e = 1; e < 8; ++e) if (logit[e] > bv) { bv = logit[e]; be = e; }
    float sc = 1.f / (1.f + expf(-bv));
    eidx[t] = be; sval[t] = sc;
    #pragma unroll
    for (int e = 0; e < 8; ++e) scores_out[(size_t)e * T_TOK + t] = (e == be) ? sc : 0.f;
  }
}

// ---------------- plan: counts, 128-aligned segments, slots, PAIR tiles ---
// pairs[i] = {rowA, rowB, expert(-1=shared), valid}
__global__ __launch_bounds__(256) void plan_kernel(
    const int* __restrict__ eidx, int* __restrict__ row2tok, int4* __restrict__ pairs)
{
  __shared__ int cnt[8];
  __shared__ int slot[8];
  const int tid = threadIdx.x;
  if (tid < 8) cnt[tid] = 0;
  __syncthreads();
  for (int t = tid; t < T_TOK; t += 256) atomicAdd(&cnt[eidx[t]], 1);
  __syncthreads();
  if (tid == 0) {
    int np = 0;
    for (int i = 0; i < 8; ++i) pairs[np++] = make_int4(i * 256, i * 256 + 128, -1, 1);
    int o = 0;
    for (int e = 0; e < 8; ++e) {
      slot[e] = o;
      int cap = (cnt[e] + 127) & ~127;
      int nt = cap / 128;
      for (int j = 0; j < nt; j += 2) {
        int ra = T_TOK + o + j * 128;
        int rb = (j + 1 < nt) ? ra + 128 : ZROW;
        pairs[np++] = make_int4(ra, rb, e, 1);
      }
      o += cap;
    }
    for (; np < NP2; ++np) pairs[np] = make_int4(ZROW, ZROW, 0, 0);
  }
  for (int r = tid; r < RROWS; r += 256) row2tok[r] = -1;
  __syncthreads();
  for (int t = tid; t < T_TOK; t += 256) {
    int e = eidx[t];
    int s = atomicAdd(&slot[e], 1);
    row2tok[s] = t;
  }
}

// ---------------- gather: X'[slot] = score * hs[tok] (bf16), 0 for pad ----
__global__ __launch_bounds__(256) void gather_kernel(
    const float* __restrict__ hs, const int* __restrict__ row2tok,
    const float* __restrict__ sval, ushort* __restrict__ Xall)
{
  const int r = blockIdx.x;
  const int t = row2tok[r];
  const int c0 = threadIdx.x * 4;
  ushort4 o;
  if (t >= 0) {
    const float sc = sval[t];
    float4 v = *(const float4*)(hs + (size_t)t * HDIM + c0);
    o.x = f2bf(sc * v.x); o.y = f2bf(sc * v.y); o.z = f2bf(sc * v.z); o.w = f2bf(sc * v.w);
  } else { o.x = o.y = o.z = o.w = 0; }
  *(ushort4*)(Xall + (size_t)(T_TOK + r) * HDIM + c0) = o;
}

// ---------------- GEMM1: act = silu(X*Wg^T) * (X*Wu^T), bf16 out ---------
// FULL-DMA: 256x128 tile, 1024 thr / 16 waves, wave 64x32 dual-acc.
// A (bf16) AND B (fp32) both via global_load_lds, triple-buffered, staged
// 2 steps ahead. B LDS is row-major [128][32] fp32 with XOR-chunk swizzle
// (chunk_g = chunk_d ^ (row&7)) applied on BOTH the global source and the
// fragment read (rule #21) -> coalescing preserved, conflict-free reads.
// Fragments convert fp32->bf16 on read via v_cvt_pk. SYNCV(3)/step.
#define STAGE1(AP, GP, UP, k0) { \
  gld16((AP) + alds0, asrc0 + (k0)); \
  gld16f((GP) + blds0, gsrc + (k0)); \
  gld16f((UP) + blds0, usrc + (k0)); }

#define BFRAG(DST, BASE, N) { \
  const float* bp_ = (BASE) + (wn * 32 + (N) * 16 + (lane & 15)) * 32; \
  float4 lo_ = *(const float4*)(bp_ + dlo4); \
  float4 hi_ = *(const float4*)(bp_ + dhi4); \
  uint4 uu_; \
  uu_.x = cvtpk(lo_.x, lo_.y); uu_.y = cvtpk(lo_.z, lo_.w); \
  uu_.z = cvtpk(hi_.x, hi_.y); uu_.w = cvtpk(hi_.z, hi_.w); \
  DST = *(bf16x8*)&uu_; }

#define READ1X(AP, GP, UP) \
  bf16x8 af[4], gf[2], uf[2]; \
  _Pragma("unroll") \
  for (int m = 0; m < 4; ++m) af[m] = *(const bf16x8*)((AP) + (wm*4+m)*512 + lp); \
  _Pragma("unroll") \
  for (int n = 0; n < 2; ++n) { BFRAG(gf[n], GP, n); BFRAG(uf[n], UP, n); }

#define MFMA1 \
  _Pragma("unroll") \
  for (int m = 0; m < 4; ++m) { \
    _Pragma("unroll") \
    for (int n = 0; n < 2; ++n) { \
      accg[m][n] = __builtin_amdgcn_mfma_f32_16x16x32_bf16(af[m], gf[n], accg[m][n], 0, 0, 0); \
      accu[m][n] = __builtin_amdgcn_mfma_f32_16x16x32_bf16(af[m], uf[n], accu[m][n], 0, 0, 0); } }

#define ROT3 { \
  ushort* at_ = aR; aR = aM; aM = aS; aS = at_; \
  float* bt_ = bgR; bgR = bgM; bgM = bgS; bgS = bt_; \
  bt_ = buR; buR = buM; buM = buS; buS = bt_; }

__global__ __launch_bounds__(1024, 1) void gemm1_kernel(
    const ushort* __restrict__ Xall,
    const float* __restrict__ w_gate, const float* __restrict__ w_up,
    const float* __restrict__ ws_gate, const float* __restrict__ ws_up,
    const int4* __restrict__ pairs, ushort* __restrict__ actall)
{
  __shared__ __align__(16) ushort As[3][8192];   // 256x32 bf16 per buf
  __shared__ __align__(16) float  Bg[3][4096];   // 128x32 fp32 per buf
  __shared__ __align__(16) float  Bu[3][4096];

  // XCD panel-serialized order: XCD j (= b%8) sweeps all 24 pairs of panel j.
  const int b0 = blockIdx.x;
  const int j = b0 & 7, s0 = b0 >> 3;
  const int panel = j + 8 * (s0 / NP2);
  const int4 td = pairs[s0 % NP2];
  if (td.w == 0) return;
  const int r0a = td.x, r0b = td.y, e = td.z;
  const float* __restrict__ gbase = (e < 0) ? ws_gate : w_gate + (size_t)e * IDIM * HDIM;
  const float* __restrict__ ubase = (e < 0) ? ws_up   : w_up   + (size_t)e * IDIM * HDIM;
  const int col0 = panel * 128;

  const int tid = threadIdx.x;
  const int lane = tid & 63;
  const int w = tid >> 6;            // 16 waves
  const int wm = w >> 2, wn = w & 3; // wave tile: rows wm*64, cols wn*32

  // B staging: thread -> row tid>>3 (128 rows), dest chunk tid&7 (4 floats);
  // fetches global chunk (tid&7)^(row&7)  [XOR swizzle, same line -> coalesced]
  const int brow = tid >> 3;
  const int bchg = (tid & 7) ^ (brow & 7);
  const float* gsrc = gbase + (size_t)(col0 + brow) * HDIM + bchg * 4;
  const float* usrc = ubase + (size_t)(col0 + brow) * HDIM + bchg * 4;
  const int blds0 = tid * 4;   // float units: row-major [128][32]

  // A staging: wave w covers rowgroup w (16 rows); lane l -> row (l&15), kc=l>>4
  const size_t abs0 = (w < 8) ? (size_t)(r0a + w * 16 + (lane & 15))
                              : (size_t)(r0b + (w - 8) * 16 + (lane & 15));
  const ushort* asrc0 = Xall + abs0 * HDIM + (lane >> 4) * 8;
  const int alds0 = w * 512 + lane * 8;

  ushort* aR = &As[0][0]; ushort* aM = &As[1][0]; ushort* aS = &As[2][0];
  float* bgR = &Bg[0][0]; float* bgM = &Bg[1][0]; float* bgS = &Bg[2][0];
  float* buR = &Bu[0][0]; float* buM = &Bu[1][0]; float* buS = &Bu[2][0];

  const int lp = (lane >> 4) * 128 + (lane & 15) * 8;
  const int dlo = (((lane >> 4) << 1)) ^ (lane & 7);   // swizzled chunk of k-lo
  const int dlo4 = dlo * 4;
  const int dhi4 = (dlo ^ 1) * 4;                      // k-hi chunk
  f32x4 accg[4][2] = {};
  f32x4 accu[4][2] = {};

  // prologue: stage step0 and step1 (3 DMAs each); drain step0's before loop
  STAGE1(aR, bgR, buR, 0);
  STAGE1(aM, bgM, buM, BK);
  SYNCV(3);

  const int NS = HDIM / BK;  // 32
  for (int s = 0; s < NS - 2; ++s) {
    STAGE1(aS, bgS, buS, (s + 2) * BK);
    READ1X(aR, bgR, buR);
    MFMA1;
    SYNCV(3);    // drain step s+1's DMAs (oldest), keep this step's
    ROT3;
  }
  {   // step NS-2: nothing left to stage; drain the last DMAs
    READ1X(aR, bgR, buR);
    MFMA1;
    SYNCV(0);
    ROT3;
  }
  {   // step NS-1: compute only
    READ1X(aR, bgR, buR);
    MFMA1;
  }

  const int prbase = wm * 64 + ((lane >> 4) << 2);
  const int cbase = col0 + wn * 32 + (lane & 15);
  #pragma unroll
  for (int m = 0; m < 4; ++m)
    #pragma unroll
    for (int n = 0; n < 2; ++n)
      #pragma unroll
      for (int j2 = 0; j2 < 4; ++j2) {
        const int pr = prbase + m * 16 + j2;
        const size_t ar = (wm < 2) ? (size_t)(r0a + pr) : (size_t)(r0b + pr - 128);
        float g = accg[m][n][j2];
        float u = accu[m][n][j2];
        float sv = g / (1.f + __expf(-g)) * u;   // silu(g)*u
        actall[ar * IDIM + cbase + n * 16] = f2bf(sv);
      }
}

// ---------------- GEMM2: out = act * Wd^T; shared->d_out, routed->bufr ---
// ROUND-6 VERBATIM: 256x128 tile, 512 thr / 8 waves, wave 64x64 single acc,
// 2-buffer A+B, pre-MFMA WRITEB of landed regs, SYNCV(2), 48 KB LDS.
#define LOADB2(S, k0) { \
  const float4* bp_ = (const float4*)(bptr + (k0)); \
  br##S[0] = bp_[0]; br##S[1] = bp_[1]; }

#define WRITEB2(S, B) { *(uint4*)&Bs[B][woff2] = cvt8(br##S[0], br##S[1]); }

#define STAGEA2(B, k0) { \
  gld16(&As[B][alds0], asrc0 + (k0)); \
  gld16(&As[B][alds1], asrc1 + (k0)); }

#define READ2(B) \
  bf16x8 af[4], bfr[4]; \
  _Pragma("unroll") \
  for (int m = 0; m < 4; ++m) af[m] = *(const bf16x8*)&As[B][(wm*4+m)*512 + lp]; \
  _Pragma("unroll") \
  for (int n = 0; n < 4; ++n) bfr[n] = *(const bf16x8*)&Bs[B][(wn*4+n)*512 + lp];

#define MFMA2 \
  _Pragma("unroll") \
  for (int m = 0; m < 4; ++m) { \
    _Pragma("unroll") \
    for (int n = 0; n < 4; ++n) \
      acc[m][n] = __builtin_amdgcn_mfma_f32_16x16x32_bf16(af[m], bfr[n], acc[m][n], 0, 0, 0); }

__global__ __launch_bounds__(512, 1) void gemm2_kernel(
    const ushort* __restrict__ actall,
    const float* __restrict__ w_down, const float* __restrict__ ws_down,
    const int4* __restrict__ pairs, const int* __restrict__ row2tok,
    float* __restrict__ out, float* __restrict__ bufr)
{
  __shared__ __align__(16) ushort As[2][8192];
  __shared__ __align__(16) ushort Bs[2][4096];

  // XCD j (= b%8) owns col-panel j for all pairs -> one down-panel per L2.
  const int b0 = blockIdx.x;
  const int panel = b0 & 7;
  const int4 td = pairs[b0 >> 3];
  if (td.w == 0) return;
  const int r0a = td.x, r0b = td.y, e = td.z;
  const float* __restrict__ bbase = (e < 0) ? ws_down : w_down + (size_t)e * HDIM * IDIM;
  const int col0 = panel * 128;

  const int tid = threadIdx.x;
  const int lane = tid & 63;
  const int w = tid >> 6;            // 8 waves
  const int wm = w >> 1, wn = w & 1; // wave tile: rows wm*64, cols wn*64

  // B staging: thread -> row tid>>2 (128 rows), kc = tid&3 (8 floats)
  const int brow = tid >> 2, kcb = tid & 3;
  const float* bptr = bbase + (size_t)(col0 + brow) * IDIM + kcb * 8;
  const int woff2 = soff(brow, kcb);

  // A staging: wave w covers pair-rows [w*32, w*32+32)
  const int arow = w * 32 + (lane & 15);
  const size_t abs0 = (w < 4) ? (size_t)(r0a + arow) : (size_t)(r0b + arow - 128);
  const ushort* asrc0 = actall + abs0 * IDIM + (lane >> 4) * 8;
  const ushort* asrc1 = asrc0 + (size_t)16 * IDIM;
  const int alds0 = w * 1024 + lane * 8;
  const int alds1 = alds0 + 512;

  float4 br0[2], br1[2];
  const int lp = (lane >> 4) * 128 + (lane & 15) * 8;
  f32x4 acc[4][4] = {};

  STAGEA2(0, 0);
  __builtin_amdgcn_sched_barrier(0);
  LOADB2(0, 0);
  WRITEB2(0, 0);
  LOADB2(1, BK);
  SYNCV(2);

  const int NS = IDIM / BK;  // 128
  for (int kk = 0; kk < NS / 2 - 1; ++kk) {
    const int k = kk * 2;
    {   // even: buf0
      READ2(0);
      STAGEA2(1, (k + 1) * BK);
      __builtin_amdgcn_sched_barrier(0);
      WRITEB2(1, 1);
      LOADB2(0, (k + 2) * BK);
      MFMA2;
      SYNCV(2);
    }
    {   // odd: buf1
      READ2(1);
      STAGEA2(0, (k + 2) * BK);
      __builtin_amdgcn_sched_barrier(0);
      WRITEB2(0, 0);
      LOADB2(1, (k + 3) * BK);
      MFMA2;
      SYNCV(2);
    }
  }
  {   // step NS-2
    READ2(0);
    STAGEA2(1, (NS - 1) * BK);
    __builtin_amdgcn_sched_barrier(0);
    WRITEB2(1, 1);
    MFMA2;
    SYNCV(0);
  }
  {   // step NS-1
    READ2(1);
    MFMA2;
  }

  const int prbase = wm * 64 + ((lane >> 4) << 2);
  const int cbase = col0 + wn * 64 + (lane & 15);
  #pragma unroll
  for (int m = 0; m < 4; ++m)
    #pragma unroll
    for (int j2 = 0; j2 < 4; ++j2) {
      const int pr = prbase + m * 16 + j2;
      const int ar = (wm < 2) ? (r0a + pr) : (r0b + pr - 128);
      if (e < 0) {
        #pragma unroll
        for (int n = 0; n < 4; ++n)
          out[(size_t)ar * HDIM + cbase + n * 16] = acc[m][n][j2];
      } else {
        const int t = row2tok[ar - T_TOK];
        if (t >= 0) {
          #pragma unroll
          for (int n = 0; n < 4; ++n)
            bufr[(size_t)t * HDIM + cbase + n * 16] = acc[m][n][j2];
        }
      }
    }
}

// ---------------- final: out += routed ------------------------------------
__global__ __launch_bounds__(256) void add_kernel(
    float* __restrict__ out, const float* __restrict__ bufr)
{
  const size_t i = ((size_t)blockIdx.x * 256 + threadIdx.x) * 4;
  float4 a = *(float4*)(out + i);
  const float4 b = *(const float4*)(bufr + i);
  a.x += b.x; a.y += b.y; a.z += b.z; a.w += b.w;
  *(float4*)(out + i) = a;
}

extern "C" void kernel_launch(void* const* d_in, const int* in_sizes, int n_in,
                              void* d_out, int out_size, void* d_ws, size_t ws_size,
                              hipStream_t stream)
{
  const float* hs      = (const float*)d_in[0];
  const float* rw      = (const float*)d_in[1];
  const float* w_gate  = (const float*)d_in[2];
  const float* w_up    = (const float*)d_in[3];
  const float* w_down  = (const float*)d_in[4];
  const float* ws_gate = (const float*)d_in[5];
  const float* ws_up   = (const float*)d_in[6];
  const float* ws_down = (const float*)d_in[7];

  float* out = (float*)d_out;
  float* scores_out = out + (size_t)T_TOK * HDIM;

  char* ws = (char*)d_ws;
  ushort* Xall   = (ushort*)ws;                       // 5248*1024*2 = 10747904
  ushort* actall = (ushort*)(ws + 10747904);          // 5248*4096*2 = 42991616
  float*  bufr   = (float*)(ws + 53739520);           // 8388608
  int*    eidx   = (int*)(ws + 62128128);             // 8192
  float*  sval   = (float*)(ws + 62136320);           // 8192
  int*    r2t    = (int*)(ws + 62144512);             // 12800
  int4*   pairs  = (int4*)(ws + 62157312);            // 384

  router_kernel<<<T_TOK / 4, 256, 0, stream>>>(hs, rw, Xall, scores_out, eidx, sval);
  plan_kernel<<<1, 256, 0, stream>>>(eidx, r2t, pairs);
  gather_kernel<<<RROWS, 256, 0, stream>>>(hs, r2t, sval, Xall);
  gemm1_kernel<<<(IDIM / 128) * NP2, 1024, 0, stream>>>(
      Xall, w_gate, w_up, ws_gate, ws_up, pairs, actall);
  gemm2_kernel<<<(HDIM / 128) * NP2, 512, 0, stream>>>(
      actall, w_down, ws_down, pairs, r2t, out, bufr);
  add_kernel<<<(T_TOK * HDIM) / 1024, 256, 0, stream>>>(out, bufr);
}

// Round 14
// 295.465 us; speedup vs baseline: 1.1854x; 1.1854x over previous
//
#include <hip/hip_runtime.h>
#include <hip/hip_bf16.h>
#include <math.h>

#define T_TOK 2048
#define HDIM 1024
#define IDIM 4096
#define NEXP 8
#define RROWS 3200    // 3072 usable routed rows + 128 guaranteed-zero dummy rows
#define AROWS 5248    // 2048 shared + RROWS
#define ZROW  5120    // absolute row of the 128 dummy zero rows (= T_TOK + 3072)
#define NP2   24      // pair-tile entries: 8 shared + <=15 routed + pad
#define BK 32

typedef unsigned int uint;
typedef unsigned short ushort;
typedef __attribute__((ext_vector_type(4))) float f32x4;
typedef __attribute__((ext_vector_type(8))) short bf16x8;

__device__ __forceinline__ ushort f2bf(float f) {
  union { float f; uint u; } c; c.f = f;
  uint u = c.u;
  return (ushort)((u + 0x7FFFu + ((u >> 16) & 1u)) >> 16);  // RNE
}
__device__ __forceinline__ uint cvtpk(float a, float b) {
  uint r;
  asm("v_cvt_pk_bf16_f32 %0, %1, %2" : "=v"(r) : "v"(a), "v"(b));
  return r;
}
__device__ __forceinline__ uint4 cvt8(const float4 a, const float4 b) {
  uint4 r;
  r.x = cvtpk(a.x, a.y); r.y = cvtpk(a.z, a.w);
  r.z = cvtpk(b.x, b.y); r.w = cvtpk(b.z, b.w);
  return r;
}
// async global->LDS, 16B per lane; LDS dest is wave-uniform base + lane*16
__device__ __forceinline__ void gld16(ushort* lds, const ushort* g) {
  __builtin_amdgcn_global_load_lds(
      (const __attribute__((address_space(1))) uint*)g,
      (__attribute__((address_space(3))) uint*)lds, 16, 0, 0);
}
// LDS tile layout: 16B slot (row,kc) -> ushort offset (row>>4)*512 + kc*128 + (row&15)*8
__device__ __forceinline__ int soff(int row, int kc) {
  return ((row >> 4) << 9) + (kc << 7) + ((row & 15) << 3);
}

// counted-vmcnt barrier: keep newest N vmem ops in flight across the barrier
#define SYNCV(N) { \
  __builtin_amdgcn_sched_barrier(0); \
  asm volatile("s_waitcnt vmcnt(" #N ") lgkmcnt(0)" ::: "memory"); \
  __builtin_amdgcn_s_barrier(); \
  __builtin_amdgcn_sched_barrier(0); }

// ---------------- router: logits, top-1, sigmoid, scores out, hs->bf16 ----
__global__ __launch_bounds__(256) void router_kernel(
    const float* __restrict__ hs, const float* __restrict__ rw,
    ushort* __restrict__ Xall, float* __restrict__ scores_out,
    int* __restrict__ eidx, float* __restrict__ sval)
{
  const int wave = threadIdx.x >> 6;
  const int lane = threadIdx.x & 63;
  const int t = blockIdx.x * 4 + wave;
  const float* row = hs + (size_t)t * HDIM;
  float v[16];
  #pragma unroll
  for (int i = 0; i < 16; ++i) {
    v[i] = row[lane + 64 * i];
    Xall[(size_t)t * HDIM + lane + 64 * i] = f2bf(v[i]);
  }
  float logit[8];
  #pragma unroll
  for (int e = 0; e < 8; ++e) {
    const float* wr = rw + e * HDIM;
    float s = 0.f;
    #pragma unroll
    for (int i = 0; i < 16; ++i) s += v[i] * wr[lane + 64 * i];
    #pragma unroll
    for (int off = 32; off; off >>= 1) s += __shfl_xor(s, off, 64);
    logit[e] = s;
  }
  if (lane == 0) {
    int be = 0; float bv = logit[0];
    #pragma unroll
    for (int e = 1; e < 8; ++e) if (logit[e] > bv) { bv = logit[e]; be = e; }
    float sc = 1.f / (1.f + expf(-bv));
    eidx[t] = be; sval[t] = sc;
    #pragma unroll
    for (int e = 0; e < 8; ++e) scores_out[(size_t)e * T_TOK + t] = (e == be) ? sc : 0.f;
  }
}

// ---------------- plan: counts, 128-aligned segments, slots, PAIR tiles ---
// pairs[i] = {rowA, rowB, expert(-1=shared), valid}
__global__ __launch_bounds__(256) void plan_kernel(
    const int* __restrict__ eidx, int* __restrict__ row2tok, int4* __restrict__ pairs)
{
  __shared__ int cnt[8];
  __shared__ int slot[8];
  const int tid = threadIdx.x;
  if (tid < 8) cnt[tid] = 0;
  __syncthreads();
  for (int t = tid; t < T_TOK; t += 256) atomicAdd(&cnt[eidx[t]], 1);
  __syncthreads();
  if (tid == 0) {
    int np = 0;
    for (int i = 0; i < 8; ++i) pairs[np++] = make_int4(i * 256, i * 256 + 128, -1, 1);
    int o = 0;
    for (int e = 0; e < 8; ++e) {
      slot[e] = o;
      int cap = (cnt[e] + 127) & ~127;
      int nt = cap / 128;
      for (int j = 0; j < nt; j += 2) {
        int ra = T_TOK + o + j * 128;
        int rb = (j + 1 < nt) ? ra + 128 : ZROW;
        pairs[np++] = make_int4(ra, rb, e, 1);
      }
      o += cap;
    }
    for (; np < NP2; ++np) pairs[np] = make_int4(ZROW, ZROW, 0, 0);
  }
  for (int r = tid; r < RROWS; r += 256) row2tok[r] = -1;
  __syncthreads();
  for (int t = tid; t < T_TOK; t += 256) {
    int e = eidx[t];
    int s = atomicAdd(&slot[e], 1);
    row2tok[s] = t;
  }
}

// ---------------- gather: X'[slot] = score * hs[tok] (bf16), 0 for pad ----
__global__ __launch_bounds__(256) void gather_kernel(
    const float* __restrict__ hs, const int* __restrict__ row2tok,
    const float* __restrict__ sval, ushort* __restrict__ Xall)
{
  const int r = blockIdx.x;
  const int t = row2tok[r];
  const int c0 = threadIdx.x * 4;
  ushort4 o;
  if (t >= 0) {
    const float sc = sval[t];
    float4 v = *(const float4*)(hs + (size_t)t * HDIM + c0);
    o.x = f2bf(sc * v.x); o.y = f2bf(sc * v.y); o.z = f2bf(sc * v.z); o.w = f2bf(sc * v.w);
  } else { o.x = o.y = o.z = o.w = 0; }
  *(ushort4*)(Xall + (size_t)(T_TOK + r) * HDIM + c0) = o;
}

// ---------------- GEMM1: act = silu(X*Wg^T) * (X*Wu^T), bf16 out ---------
// ROUND-9 VERBATIM: 256x128 tile, 1024 thr / 16 waves, wave 64x32 dual-acc.
// A: triple-buffered global_load_lds, staged 2 steps ahead.
// B: fp32 regs loaded 2 steps ahead; cvt+ds_write AFTER MFMA.
// Steady-state barrier: vmcnt(3).
#define LOADB1(S, k0) { \
  gr##S = *(const float4*)(gptr + (k0)); \
  ur##S = *(const float4*)(uptr + (k0)); }

#define WRITEB1(S, B) { \
  *(uint2*)&Bg[B][woff] = make_uint2(cvtpk(gr##S.x, gr##S.y), cvtpk(gr##S.z, gr##S.w)); \
  *(uint2*)&Bu[B][woff] = make_uint2(cvtpk(ur##S.x, ur##S.y), cvtpk(ur##S.z, ur##S.w)); }

#define STAGEA1(ABASE, k0) { gld16((ABASE) + alds0, asrc0 + (k0)); }

#define READ1(ABASE, B) \
  bf16x8 af[4], gf[2], uf[2]; \
  _Pragma("unroll") \
  for (int m = 0; m < 4; ++m) af[m] = *(const bf16x8*)((ABASE) + (wm*4+m)*512 + lp); \
  _Pragma("unroll") \
  for (int n = 0; n < 2; ++n) { \
    gf[n] = *(const bf16x8*)&Bg[B][(wn*2+n)*512 + lp]; \
    uf[n] = *(const bf16x8*)&Bu[B][(wn*2+n)*512 + lp]; }

#define MFMA1 \
  _Pragma("unroll") \
  for (int m = 0; m < 4; ++m) { \
    _Pragma("unroll") \
    for (int n = 0; n < 2; ++n) { \
      accg[m][n] = __builtin_amdgcn_mfma_f32_16x16x32_bf16(af[m], gf[n], accg[m][n], 0, 0, 0); \
      accu[m][n] = __builtin_amdgcn_mfma_f32_16x16x32_bf16(af[m], uf[n], accu[m][n], 0, 0, 0); } }

#define ROTA { ushort* aT_ = aR; aR = aM; aM = aS; aS = aT_; }

__global__ __launch_bounds__(1024, 1) void gemm1_kernel(
    const ushort* __restrict__ Xall,
    const float* __restrict__ w_gate, const float* __restrict__ w_up,
    const float* __restrict__ ws_gate, const float* __restrict__ ws_up,
    const int4* __restrict__ pairs, ushort* __restrict__ actall)
{
  __shared__ __align__(16) ushort As[3][8192];
  __shared__ __align__(16) ushort Bg[2][4096];
  __shared__ __align__(16) ushort Bu[2][4096];

  // XCD panel-serialized order: XCD j (= b%8) sweeps all 24 pairs of panel j.
  const int b0 = blockIdx.x;
  const int j = b0 & 7, s = b0 >> 3;
  const int panel = j + 8 * (s / NP2);
  const int4 td = pairs[s % NP2];
  if (td.w == 0) return;
  const int r0a = td.x, r0b = td.y, e = td.z;
  const float* __restrict__ gbase = (e < 0) ? ws_gate : w_gate + (size_t)e * IDIM * HDIM;
  const float* __restrict__ ubase = (e < 0) ? ws_up   : w_up   + (size_t)e * IDIM * HDIM;
  const int col0 = panel * 128;

  const int tid = threadIdx.x;
  const int lane = tid & 63;
  const int w = tid >> 6;            // 16 waves
  const int wm = w >> 2, wn = w & 3; // wave tile: rows wm*64, cols wn*32

  // B staging: thread -> row tid>>3 (128 rows), float4 chunk tid&7 (32 floats/row)
  const int brow = tid >> 3, bch = tid & 7;
  const float* gptr = gbase + (size_t)(col0 + brow) * HDIM + bch * 4;
  const float* uptr = ubase + (size_t)(col0 + brow) * HDIM + bch * 4;
  const int woff = soff(brow, bch >> 1) + (bch & 1) * 4;  // 8B half-slot

  // A staging: wave w covers rowgroup w (16 rows); lane l -> row (l&15), kc=l>>4
  const size_t abs0 = (w < 8) ? (size_t)(r0a + w * 16 + (lane & 15))
                              : (size_t)(r0b + (w - 8) * 16 + (lane & 15));
  const ushort* asrc0 = Xall + abs0 * HDIM + (lane >> 4) * 8;
  const int alds0 = w * 512 + lane * 8;

  ushort* aR = &As[0][0];  // read this step
  ushort* aM = &As[1][0];  // read next step (DMA in flight / landed)
  ushort* aS = &As[2][0];  // stage target (step s+2)

  float4 gr0, ur0, gr1, ur1;
  const int lp = (lane >> 4) * 128 + (lane & 15) * 8;
  f32x4 accg[4][2] = {};
  f32x4 accu[4][2] = {};

  // prologue: A(0)->aR, A(1)->aM, B(0)->lds0, B(1)->regs set1
  STAGEA1(aR, 0);
  LOADB1(0, 0);
  STAGEA1(aM, BK);
  LOADB1(1, BK);
  WRITEB1(0, 0);       // auto-waits set0 regs (drains A(0) DMA too)
  SYNCV(3);            // leaves A(1) + set1 loads in flight

  const int NS = HDIM / BK;  // 32
  for (int kk = 0; kk < NS / 2 - 1; ++kk) {
    const int k = kk * 2;
    {   // even step s=k: read aR/lds0, stage A(s+2), load B(s+2), write B(s+1)
      READ1(aR, 0);
      STAGEA1(aS, (k + 2) * BK);
      LOADB1(0, (k + 2) * BK);
      MFMA1;
      WRITEB1(1, 1);   // post-MFMA: auto-wait for set1 (issued last step)
      SYNCV(3);
      ROTA;
    }
    {   // odd step s=k+1
      READ1(aR, 1);
      STAGEA1(aS, (k + 3) * BK);
      LOADB1(1, (k + 3) * BK);
      MFMA1;
      WRITEB1(0, 0);
      SYNCV(3);
      ROTA;
    }
  }
  {   // step NS-2 (even): no staging left; write B(NS-1), full drain
    READ1(aR, 0);
    MFMA1;
    WRITEB1(1, 1);
    SYNCV(0);
    ROTA;
  }
  {   // step NS-1 (odd): compute only
    READ1(aR, 1);
    MFMA1;
  }

  const int prbase = wm * 64 + ((lane >> 4) << 2);
  const int cbase = col0 + wn * 32 + (lane & 15);
  #pragma unroll
  for (int m = 0; m < 4; ++m)
    #pragma unroll
    for (int n = 0; n < 2; ++n)
      #pragma unroll
      for (int j2 = 0; j2 < 4; ++j2) {
        const int pr = prbase + m * 16 + j2;
        const size_t ar = (wm < 2) ? (size_t)(r0a + pr) : (size_t)(r0b + pr - 128);
        float g = accg[m][n][j2];
        float u = accu[m][n][j2];
        float sv = g / (1.f + __expf(-g)) * u;   // silu(g)*u
        actall[ar * IDIM + cbase + n * 16] = f2bf(sv);
      }
}

// ---------------- GEMM2: out = act * Wd^T; shared->d_out, routed->bufr ---
// ROUND-6 VERBATIM: 256x128 tile, 512 thr / 8 waves, wave 64x64 single acc,
// 2-buffer A+B, pre-MFMA WRITEB of landed regs, SYNCV(2), 48 KB LDS
// -> 2 blocks/CU co-resident (VGPR 128).
#define LOADB2(S, k0) { \
  const float4* bp_ = (const float4*)(bptr + (k0)); \
  br##S[0] = bp_[0]; br##S[1] = bp_[1]; }

#define WRITEB2(S, B) { *(uint4*)&Bs[B][woff2] = cvt8(br##S[0], br##S[1]); }

#define STAGEA2(B, k0) { \
  gld16(&As[B][alds0], asrc0 + (k0)); \
  gld16(&As[B][alds1], asrc1 + (k0)); }

#define READ2(B) \
  bf16x8 af[4], bfr[4]; \
  _Pragma("unroll") \
  for (int m = 0; m < 4; ++m) af[m] = *(const bf16x8*)&As[B][(wm*4+m)*512 + lp]; \
  _Pragma("unroll") \
  for (int n = 0; n < 4; ++n) bfr[n] = *(const bf16x8*)&Bs[B][(wn*4+n)*512 + lp];

#define MFMA2 \
  _Pragma("unroll") \
  for (int m = 0; m < 4; ++m) { \
    _Pragma("unroll") \
    for (int n = 0; n < 4; ++n) \
      acc[m][n] = __builtin_amdgcn_mfma_f32_16x16x32_bf16(af[m], bfr[n], acc[m][n], 0, 0, 0); }

__global__ __launch_bounds__(512, 1) void gemm2_kernel(
    const ushort* __restrict__ actall,
    const float* __restrict__ w_down, const float* __restrict__ ws_down,
    const int4* __restrict__ pairs, const int* __restrict__ row2tok,
    float* __restrict__ out, float* __restrict__ bufr)
{
  __shared__ __align__(16) ushort As[2][8192];
  __shared__ __align__(16) ushort Bs[2][4096];

  // XCD j (= b%8) owns col-panel j for all pairs -> one down-panel per L2.
  const int b0 = blockIdx.x;
  const int panel = b0 & 7;
  const int4 td = pairs[b0 >> 3];
  if (td.w == 0) return;
  const int r0a = td.x, r0b = td.y, e = td.z;
  const float* __restrict__ bbase = (e < 0) ? ws_down : w_down + (size_t)e * HDIM * IDIM;
  const int col0 = panel * 128;

  const int tid = threadIdx.x;
  const int lane = tid & 63;
  const int w = tid >> 6;            // 8 waves
  const int wm = w >> 1, wn = w & 1; // wave tile: rows wm*64, cols wn*64

  // B staging: thread -> row tid>>2 (128 rows), kc = tid&3 (8 floats)
  const int brow = tid >> 2, kcb = tid & 3;
  const float* bptr = bbase + (size_t)(col0 + brow) * IDIM + kcb * 8;
  const int woff2 = soff(brow, kcb);

  // A staging: wave w covers pair-rows [w*32, w*32+32)
  const int arow = w * 32 + (lane & 15);
  const size_t abs0 = (w < 4) ? (size_t)(r0a + arow) : (size_t)(r0b + arow - 128);
  const ushort* asrc0 = actall + abs0 * IDIM + (lane >> 4) * 8;
  const ushort* asrc1 = asrc0 + (size_t)16 * IDIM;
  const int alds0 = w * 1024 + lane * 8;
  const int alds1 = alds0 + 512;

  float4 br0[2], br1[2];
  const int lp = (lane >> 4) * 128 + (lane & 15) * 8;
  f32x4 acc[4][4] = {};

  STAGEA2(0, 0);
  __builtin_amdgcn_sched_barrier(0);
  LOADB2(0, 0);
  WRITEB2(0, 0);
  LOADB2(1, BK);
  SYNCV(2);

  const int NS = IDIM / BK;  // 128
  for (int kk = 0; kk < NS / 2 - 1; ++kk) {
    const int k = kk * 2;
    {   // even: buf0
      READ2(0);
      STAGEA2(1, (k + 1) * BK);
      __builtin_amdgcn_sched_barrier(0);
      WRITEB2(1, 1);
      LOADB2(0, (k + 2) * BK);
      MFMA2;
      SYNCV(2);
    }
    {   // odd: buf1
      READ2(1);
      STAGEA2(0, (k + 2) * BK);
      __builtin_amdgcn_sched_barrier(0);
      WRITEB2(0, 0);
      LOADB2(1, (k + 3) * BK);
      MFMA2;
      SYNCV(2);
    }
  }
  {   // step NS-2
    READ2(0);
    STAGEA2(1, (NS - 1) * BK);
    __builtin_amdgcn_sched_barrier(0);
    WRITEB2(1, 1);
    MFMA2;
    SYNCV(0);
  }
  {   // step NS-1
    READ2(1);
    MFMA2;
  }

  const int prbase = wm * 64 + ((lane >> 4) << 2);
  const int cbase = col0 + wn * 64 + (lane & 15);
  #pragma unroll
  for (int m = 0; m < 4; ++m)
    #pragma unroll
    for (int j2 = 0; j2 < 4; ++j2) {
      const int pr = prbase + m * 16 + j2;
      const int ar = (wm < 2) ? (r0a + pr) : (r0b + pr - 128);
      if (e < 0) {
        #pragma unroll
        for (int n = 0; n < 4; ++n)
          out[(size_t)ar * HDIM + cbase + n * 16] = acc[m][n][j2];
      } else {
        const int t = row2tok[ar - T_TOK];
        if (t >= 0) {
          #pragma unroll
          for (int n = 0; n < 4; ++n)
            bufr[(size_t)t * HDIM + cbase + n * 16] = acc[m][n][j2];
        }
      }
    }
}

// ---------------- final: out += routed ------------------------------------
__global__ __launch_bounds__(256) void add_kernel(
    float* __restrict__ out, const float* __restrict__ bufr)
{
  const size_t i = ((size_t)blockIdx.x * 256 + threadIdx.x) * 4;
  float4 a = *(float4*)(out + i);
  const float4 b = *(const float4*)(bufr + i);
  a.x += b.x; a.y += b.y; a.z += b.z; a.w += b.w;
  *(float4*)(out + i) = a;
}

extern "C" void kernel_launch(void* const* d_in, const int* in_sizes, int n_in,
                              void* d_out, int out_size, void* d_ws, size_t ws_size,
                              hipStream_t stream)
{
  const float* hs      = (const float*)d_in[0];
  const float* rw      = (const float*)d_in[1];
  const float* w_gate  = (const float*)d_in[2];
  const float* w_up    = (const float*)d_in[3];
  const float* w_down  = (const float*)d_in[4];
  const float* ws_gate = (const float*)d_in[5];
  const float* ws_up   = (const float*)d_in[6];
  const float* ws_down = (const float*)d_in[7];

  float* out = (float*)d_out;
  float* scores_out = out + (size_t)T_TOK * HDIM;

  char* ws = (char*)d_ws;
  ushort* Xall   = (ushort*)ws;                       // 5248*1024*2 = 10747904
  ushort* actall = (ushort*)(ws + 10747904);          // 5248*4096*2 = 42991616
  float*  bufr   = (float*)(ws + 53739520);           // 8388608
  int*    eidx   = (int*)(ws + 62128128);             // 8192
  float*  sval   = (float*)(ws + 62136320);           // 8192
  int*    r2t    = (int*)(ws + 62144512);             // 12800
  int4*   pairs  = (int4*)(ws + 62157312);            // 384

  router_kernel<<<T_TOK / 4, 256, 0, stream>>>(hs, rw, Xall, scores_out, eidx, sval);
  plan_kernel<<<1, 256, 0, stream>>>(eidx, r2t, pairs);
  gather_kernel<<<RROWS, 256, 0, stream>>>(hs, r2t, sval, Xall);
  gemm1_kernel<<<(IDIM / 128) * NP2, 1024, 0, stream>>>(
      Xall, w_gate, w_up, ws_gate, ws_up, pairs, actall);
  gemm2_kernel<<<(HDIM / 128) * NP2, 512, 0, stream>>>(
      actall, w_down, ws_down, pairs, r2t, out, bufr);
  add_kernel<<<(T_TOK * HDIM) / 1024, 256, 0, stream>>>(out, bufr);
}